// Round 16
// baseline (123.740 us; speedup 1.0000x reference)
//
#include <hip/hip_runtime.h>
#include <hip/hip_bf16.h>
#include <cmath>

#define Bb   2
#define Tseq 2048
#define NH   16
#define DM   1024

using f32x4 = __attribute__((ext_vector_type(4))) float;
using s16x8 = __attribute__((ext_vector_type(8))) short;
using s16x4 = __attribute__((ext_vector_type(4))) short;

typedef const __attribute__((address_space(1))) unsigned char* as1p;
typedef __attribute__((address_space(3))) unsigned char* as3p;

static __device__ __forceinline__ void gload_lds16(const void* g, void* l){
  __builtin_amdgcn_global_load_lds((as1p)g, (as3p)l, 16, 0, 0);
}

// PV MFMA: 16x16x16 bf16 (K=16). B-frag needs P[k=g*4+j][q=ln] == QK^T output s[nt][r].
#if defined(__has_builtin)
#if __has_builtin(__builtin_amdgcn_mfma_f32_16x16x16bf16_1k)
#define MFMA16(acc, va, pb) (acc) = __builtin_amdgcn_mfma_f32_16x16x16bf16_1k((va), (pb), (acc), 0, 0, 0)
#endif
#endif
#ifndef MFMA16
#define MFMA16(acc, va, pb) asm volatile("s_nop 1\n\tv_mfma_f32_16x16x16_bf16 %0, %1, %2, %0" : "+v"(acc) : "v"(va), "v"(pb))
#endif

static __device__ __forceinline__ float b2f(unsigned short u){
  union { unsigned int u; float f; } v; v.u = ((unsigned int)u) << 16; return v.f;
}
static __device__ __forceinline__ unsigned short f2b(float f){
  union { float f; unsigned int u; } v; v.f = f;
  unsigned int u = v.u;
  return (unsigned short)((u + 0x7fffu + ((u >> 16) & 1u)) >> 16);
}

// ---------------- fp32 -> bf16 convert, all three tensors in one launch ----------------
__global__ void k_convert3(const float* __restrict__ a, unsigned short* __restrict__ ab, int na,
                           const float* __restrict__ b, unsigned short* __restrict__ bb, int nb,
                           const float* __restrict__ c, unsigned short* __restrict__ cb, int nc){
  const int q0 = na >> 2, q1 = nb >> 2, q2 = nc >> 2;
  const int tot = q0 + q1 + q2;
  const int stride = gridDim.x * blockDim.x;
  for (int i = blockIdx.x * blockDim.x + threadIdx.x; i < tot; i += stride) {
    const float* src; unsigned short* dst; int j = i;
    if (j < q0) { src = a; dst = ab; }
    else { j -= q0; if (j < q1) { src = b; dst = bb; } else { j -= q1; src = c; dst = cb; } }
    float4 v = reinterpret_cast<const float4*>(src)[j];
    ushort4 o; o.x = f2b(v.x); o.y = f2b(v.y); o.z = f2b(v.z); o.w = f2b(v.w);
    reinterpret_cast<ushort4*>(dst)[j] = o;
  }
}

// ---------------- GEMM  C[m,n] = sum_k A[m,k] * W[n,k] ----------------
// BK=64, gload_lds w16 with pre-swizzled SOURCE (linear dest + inverse-swz src
// + swz read; 0 bank conflicts verified r11). XCD-chunked 1D grid.
// MODE 0: fp32 C out. MODE 2: qkv fused epilogue -- q/k get in-register RoPE
// (on-the-fly __sincosf, q pre-scaled by 0.125*log2e); v tiles are transposed
// in the (dead) As/Bs LDS and written straight to vt[b,h,d,t] (vtrans fused).
template<int MODE>
__global__ __launch_bounds__(256) void k_gemm_bt(const unsigned short* __restrict__ A,
                                                 const unsigned short* __restrict__ W,
                                                 void* __restrict__ Cout,
                                                 int M, int N, int K, int NYL,
                                                 unsigned short* __restrict__ qr,
                                                 unsigned short* __restrict__ kr,
                                                 unsigned short* __restrict__ vt){
  __shared__ unsigned short As[128*64];
  __shared__ unsigned short Bs[128*64];
  const int i = (int)blockIdx.x;
  const int xcd = i & 7, rr = i >> 3;
  const int bx = rr / NYL, by = xcd * NYL + (rr % NYL);
  const int bm = bx * 128, bn = by * 128;
  const int tid = threadIdx.x;
  const int lane = tid & 63, w = tid >> 6;
  const int wr = w >> 1, wc = w & 1;            // wave -> 64x64 quadrant
  const int g = lane >> 4, ln = lane & 15;
  f32x4 acc[4][4] = {};
  char* asb = (char*)As + w * 4096;
  char* bsb = (char*)Bs + w * 4096;
  const int lrow8 = lane >> 3;                   // 0..7: row within 8-row gload group
  const int kcolb = ((lane & 7) ^ lrow8) * 16;   // byte col in 128B row window, pre-swz
  const size_t aro = (size_t)(bm + w * 32 + lrow8) * K;
  const size_t bro = (size_t)(bn + w * 32 + lrow8) * K;
  const int xr = (ln & 7) << 4;                  // read-side XOR (row&7 == ln&7)
  for (int k0 = 0; k0 < K; k0 += 64) {
    #pragma unroll
    for (int q4 = 0; q4 < 4; ++q4) {
      gload_lds16((const char*)(A + aro + (size_t)(q4 * 8) * K + k0) + kcolb, asb + q4 * 1024);
      gload_lds16((const char*)(W + bro + (size_t)(q4 * 8) * K + k0) + kcolb, bsb + q4 * 1024);
    }
    __syncthreads();
    #pragma unroll
    for (int kk = 0; kk < 2; ++kk) {
      s16x8 af[4], bfr[4];
      const int ro = (kk * 64 + g * 16) ^ xr;
      #pragma unroll
      for (int mt = 0; mt < 4; ++mt)
        af[mt] = *reinterpret_cast<const s16x8*>((char*)As + (wr*64 + mt*16 + ln) * 128 + ro);
      #pragma unroll
      for (int nt = 0; nt < 4; ++nt)
        bfr[nt] = *reinterpret_cast<const s16x8*>((char*)Bs + (wc*64 + nt*16 + ln) * 128 + ro);
      #pragma unroll
      for (int mt = 0; mt < 4; ++mt)
        #pragma unroll
        for (int nt = 0; nt < 4; ++nt)
          acc[mt][nt] = __builtin_amdgcn_mfma_f32_16x16x32_bf16(af[mt], bfr[nt], acc[mt][nt], 0, 0, 0);
    }
    __syncthreads();
  }
  // ---------------- epilogue ----------------
  if (MODE == 0) {
    #pragma unroll
    for (int mt = 0; mt < 4; ++mt)
      #pragma unroll
      for (int nt = 0; nt < 4; ++nt)
        #pragma unroll
        for (int r = 0; r < 4; ++r) {
          int row = bm + wr*64 + mt*16 + g*4 + r;     // D: row = (lane>>4)*4 + reg
          int col = bn + wc*64 + nt*16 + ln;          // D: col = lane&15
          reinterpret_cast<float*>(Cout)[(size_t)row * N + col] = acc[mt][nt][r];
        }
  } else {
    const int region = bn >> 10;                      // 0=q, 1=k, 2=v
    if (region == 2) {
      // V transpose in dead As/Bs LDS: [dcol 0..127][t 0..127] bf16 with XOR swizzle.
      // dcol = wc*64 + nt*16 + ln; t = wr*64 + mt*16 + g*4 + r (r contiguous -> uint2).
      unsigned short* tb = wc ? Bs : As;              // 64 rows x 256B each
      #pragma unroll
      for (int nt = 0; nt < 4; ++nt) {
        const int lrow = nt * 16 + ln;
        char* rowp = (char*)tb + lrow * 256;
        const int sx = (lrow & 15) << 3;
        #pragma unroll
        for (int mt = 0; mt < 4; ++mt) {
          const int t2 = (wr*64 + mt*16 + g*4) * 2;   // byte offset, 8B-aligned
          unsigned int lo = (unsigned int)f2b(acc[mt][nt][0]) | ((unsigned int)f2b(acc[mt][nt][1]) << 16);
          unsigned int hi = (unsigned int)f2b(acc[mt][nt][2]) | ((unsigned int)f2b(acc[mt][nt][3]) << 16);
          *reinterpret_cast<uint2*>(rowp + (t2 ^ sx)) = make_uint2(lo, hi);
        }
      }
      __syncthreads();
      {
        const int dcol = tid >> 1, half = tid & 1;    // 64 t's (=128B) per thread
        unsigned short* tb2 = (dcol < 64) ? As : Bs;
        char* rowp = (char*)tb2 + (dcol & 63) * 256;
        const int sx = (dcol & 15) << 3;
        unsigned int buf[32];
        #pragma unroll
        for (int k = 0; k < 16; ++k) {
          uint2 v = *reinterpret_cast<uint2*>(rowp + ((((half * 64 + k * 4) * 2) ^ sx)));
          buf[k*2] = v.x; buf[k*2+1] = v.y;
        }
        const int h0 = (bn - 2048) >> 6;
        const int hq = h0 + (dcol >> 6);
        const int dd = dcol & 63;
        const int row0 = bm + half * 64;
        const int b = row0 >> 11, t0 = row0 & (Tseq - 1);
        unsigned short* dst = vt + ((size_t)((b * NH + hq) * 64 + dd)) * Tseq + t0;
        #pragma unroll
        for (int k = 0; k < 8; ++k)
          reinterpret_cast<uint4*>(dst)[k] = make_uint4(buf[k*4], buf[k*4+1], buf[k*4+2], buf[k*4+3]);
      }
    } else {
      // RoPE in-register: dd = nt*16+ln (wc-independent); pairs (nt, nt^2) same lane.
      const float if0 = exp2f(-(float)ln        * 0.4152410118074f);
      const float if1 = exp2f(-(float)(16 + ln) * 0.4152410118074f);
      const int h = ((bn + wc * 64) >> 6) & 15;
      unsigned short* dst = (region == 0) ? qr : kr;
      // q: fold 1/sqrt(dh) AND log2(e) so attention uses native exp2
      const float qs = (region == 0) ? 0.18033688011112042f : 1.0f;
      #pragma unroll
      for (int mt = 0; mt < 4; ++mt)
        #pragma unroll
        for (int r = 0; r < 4; ++r) {
          int row = bm + wr*64 + mt*16 + g*4 + r;
          int t = row & (Tseq - 1), b = row >> 11;
          float c0, s0, c1, s1;
          __sincosf((float)t * if0, &s0, &c0);
          __sincosf((float)t * if1, &s1, &c1);
          float v0 = (acc[mt][0][r] * c0 - acc[mt][2][r] * s0) * qs;  // dd=ln
          float v1 = (acc[mt][1][r] * c1 - acc[mt][3][r] * s1) * qs;  // dd=16+ln
          float v2 = (acc[mt][2][r] * c0 + acc[mt][0][r] * s0) * qs;  // dd=32+ln
          float v3 = (acc[mt][3][r] * c1 + acc[mt][1][r] * s1) * qs;  // dd=48+ln
          size_t base = ((size_t)(b * NH + h) * Tseq + t) * 64 + ln;
          dst[base]      = f2b(v0);
          dst[base + 16] = f2b(v1);
          dst[base + 32] = f2b(v2);
          dst[base + 48] = f2b(v3);
        }
    }
  }
}

// ---------------- causal flash attention, fully-swapped, dbuf + reg-P ----------------
// 256-thr blocks (4 waves x 16 q), ONE 64-row q-tile per block: 1024 blocks,
// LDS = exactly 32KB (epilogue bounce reuses dead Ks) -> up to 5 blocks/CU.
// Longest-first dispatch (qt = 31 - (r>>2)) -> LPT refill balance. XCD-chunked
// (4 heads/XCD L2-resident). K/V reg-staged, 16B swizzle (r12/r15-proven).
// QK^T: 16x16x32 swapped. PV: 16x16x16, P in registers (exp2 + trunc-pack).
__global__ __launch_bounds__(256, 5) void k_attn(const unsigned short* __restrict__ Qr,
                                                 const unsigned short* __restrict__ Kr,
                                                 const unsigned short* __restrict__ Vt,
                                                 unsigned short* __restrict__ Ao){
  __shared__ unsigned short Ks[2][64*64];
  __shared__ unsigned short Vs[2][64*64];
  // remap: 1024 = 8 xcds x 128; r = i>>3: qt = 31-(r>>2) (longest first), head = r&3
  const int i = (int)blockIdx.x;
  const int xcd = i & 7, r = i >> 3;
  const int qt = 31 - (r >> 2);
  const int bh = xcd * 4 + (r & 3);
  const int q0 = qt * 64;
  const int ntiles = qt + 1;
  const unsigned short* Q  = Qr + (size_t)bh * Tseq * 64;
  const unsigned short* Kp = Kr + (size_t)bh * Tseq * 64;
  const unsigned short* Vp = Vt + (size_t)bh * 64 * Tseq;
  const int tid = threadIdx.x;
  const int w = tid >> 6, lane = tid & 63;
  const int g = lane >> 4, ln = lane & 15;
  // staging: 256 thr x 32B of each 8KB tile. row = tid>>2, chunk pair = (tid&3)*2
  const int srow = tid >> 2;
  const int c2 = (tid & 3) * 2;
  const int scol = c2 * 8;                          // shorts
  const int swz = (srow & 7) << 4;
  const int wb0 = srow * 128 + ((c2 * 16)      ^ swz);
  const int wb1 = srow * 128 + ((c2 * 16 + 16) ^ swz);
  // QK frag read offsets (b128)
  const int x0 = (g * 16)      ^ ((ln & 7) << 4);
  const int x1 = (64 + g * 16) ^ ((ln & 7) << 4);
  const int b = bh / NH, h = bh % NH;
  const int q0w = q0 + w * 16;

  s16x8 qf0 = *reinterpret_cast<const s16x8*>(&Q[(size_t)(q0w + ln) * 64 + g * 8]);
  s16x8 qf1 = *reinterpret_cast<const s16x8*>(&Q[(size_t)(q0w + ln) * 64 + 32 + g * 8]);

  f32x4 oacc[4] = {};
  float lsum = 0.f;

  // prologue: stage tile 0 into buf 0
  {
    const unsigned short* gk = Kp + (size_t)srow * 64 + scol;
    const unsigned short* gv = Vp + (size_t)srow * Tseq + scol;
    uint4 k0 = *reinterpret_cast<const uint4*>(gk);
    uint4 k1 = *reinterpret_cast<const uint4*>(gk + 8);
    uint4 v0 = *reinterpret_cast<const uint4*>(gv);
    uint4 v1 = *reinterpret_cast<const uint4*>(gv + 8);
    *reinterpret_cast<uint4*>((char*)Ks[0] + wb0) = k0;
    *reinterpret_cast<uint4*>((char*)Ks[0] + wb1) = k1;
    *reinterpret_cast<uint4*>((char*)Vs[0] + wb0) = v0;
    *reinterpret_cast<uint4*>((char*)Vs[0] + wb1) = v1;
  }
  __syncthreads();
  int cur = 0;

  for (int kt = 0; kt < ntiles; ++kt) {
    const bool pre = (kt + 1 < ntiles);
    const int nxt = cur ^ 1;
    uint4 nk0, nk1, nv0, nv1;
    if (pre) {  // issue next-tile loads early; L2-hit latency hides under compute
      const unsigned short* gk = Kp + (size_t)((kt + 1) * 64 + srow) * 64 + scol;
      const unsigned short* gv = Vp + (size_t)srow * Tseq + (kt + 1) * 64 + scol;
      nk0 = *reinterpret_cast<const uint4*>(gk);
      nk1 = *reinterpret_cast<const uint4*>(gk + 8);
      nv0 = *reinterpret_cast<const uint4*>(gv);
      nv1 = *reinterpret_cast<const uint4*>(gv + 8);
    }
    // ---- QK^T swapped: s[nt] = S^T[k = kt*64+nt*16+g*4+r][q = q0w+ln] ----
    f32x4 s[4] = {};
    const char* kb = (const char*)Ks[cur];
    __builtin_amdgcn_s_setprio(1);
    #pragma unroll
    for (int nt = 0; nt < 4; ++nt) {
      s16x8 kfa = *reinterpret_cast<const s16x8*>(kb + nt * 2048 + ln * 128 + x0);
      s16x8 kfb = *reinterpret_cast<const s16x8*>(kb + nt * 2048 + ln * 128 + x1);
      s[nt] = __builtin_amdgcn_mfma_f32_16x16x32_bf16(kfa, qf0, s[nt], 0, 0, 0);
      s[nt] = __builtin_amdgcn_mfma_f32_16x16x32_bf16(kfb, qf1, s[nt], 0, 0, 0);
    }
    __builtin_amdgcn_s_setprio(0);
    // ---- causal mask (last tile only; k_rel = nt*16+g*4+r, q_rel = w*16+ln) ----
    if (kt == ntiles - 1) {
      #pragma unroll
      for (int nt = 0; nt < 4; ++nt)
        #pragma unroll
        for (int r2 = 0; r2 < 4; ++r2)
          if (nt * 16 + g * 4 + r2 > w * 16 + ln) s[nt][r2] = -1e30f;
    }
    // ---- fixed-base softmax, exp2 domain (q pre-scaled by log2e/8);
    //      raw v_exp_f32 via builtin; P packed to bf16 by truncation ----
    s16x4 pb[4];
    #pragma unroll
    for (int nt = 0; nt < 4; ++nt)
      #pragma unroll
      for (int r2 = 0; r2 < 4; ++r2) {
        float p = __builtin_amdgcn_exp2f(s[nt][r2]);
        lsum += p;
        pb[nt][r2] = (short)(__float_as_uint(p) >> 16);
      }
    // ---- PV via 16x16x16: oacc[dt] = O^T[d = dt*16+g*4+r][q = ln] ----
    const char* vb = (const char*)Vs[cur];
    __builtin_amdgcn_s_setprio(1);
    #pragma unroll
    for (int dt = 0; dt < 4; ++dt) {
      #pragma unroll
      for (int nt = 0; nt < 4; ++nt) {
        s16x4 va = *reinterpret_cast<const s16x4*>(vb + (dt * 16 + ln) * 128 + ((nt * 32 + g * 8) ^ ((ln & 7) << 4)));
        MFMA16(oacc[dt], va, pb[nt]);
      }
    }
    __builtin_amdgcn_s_setprio(0);
    // ---- write prefetched tile into other buffer; single barrier ----
    if (pre) {
      *reinterpret_cast<uint4*>((char*)Ks[nxt] + wb0) = nk0;
      *reinterpret_cast<uint4*>((char*)Ks[nxt] + wb1) = nk1;
      *reinterpret_cast<uint4*>((char*)Vs[nxt] + wb0) = nv0;
      *reinterpret_cast<uint4*>((char*)Vs[nxt] + wb1) = nv1;
    }
    __syncthreads();
    cur ^= 1;
  }

  // ---- epilogue: l-reduce, O^T -> row-major via LDS bounce (reuse dead Ks:
  //      after the final barrier no wave reads K/V again; per-wave 4KB region) ----
  float l = lsum;
  l += __shfl_xor(l, 16);
  l += __shfl_xor(l, 32);
  float inv = 1.f / l;
  unsigned short* Pw = reinterpret_cast<unsigned short*>((char*)Ks + w * 4096);
  #pragma unroll
  for (int nt = 0; nt < 4; ++nt) {
    unsigned int lo = (unsigned int)f2b(oacc[nt][0] * inv) | ((unsigned int)f2b(oacc[nt][1] * inv) << 16);
    unsigned int hi = (unsigned int)f2b(oacc[nt][2] * inv) | ((unsigned int)f2b(oacc[nt][3] * inv) << 16);
    *reinterpret_cast<uint2*>(&Pw[ln * 72 + nt * 16 + g * 4]) = make_uint2(lo, hi);
  }
  asm volatile("s_waitcnt lgkmcnt(0)" ::: "memory");
  __builtin_amdgcn_sched_barrier(0);
  const int rr2 = lane >> 2;                // 0..15: q-row within wave tile
  const int cc = (lane & 3) * 8;            // short offset
  uint4 ov0 = *reinterpret_cast<const uint4*>(&Pw[rr2 * 72 + cc]);
  uint4 ov1 = *reinterpret_cast<const uint4*>(&Pw[rr2 * 72 + cc + 32]);
  int t = q0w + rr2;
  unsigned short* orow = &Ao[((size_t)(b * Tseq + t) * DM) + h * 64];
  *reinterpret_cast<uint4*>(orow + cc)      = ov0;
  *reinterpret_cast<uint4*>(orow + cc + 32) = ov1;
}

extern "C" void kernel_launch(void* const* d_in, const int* in_sizes, int n_in,
                              void* d_out, int out_size, void* d_ws, size_t ws_size,
                              hipStream_t stream) {
  const float* x    = (const float*)d_in[0];
  const float* qkvw = (const float*)d_in[1];
  const float* outw = (const float*)d_in[2];
  float* out = (float*)d_out;
  char* ws = (char*)d_ws;
  size_t off = 0;
  auto alloc = [&](size_t bytes)->void*{ void* p = ws + off; off += (bytes + 255) & ~(size_t)255; return p; };
  unsigned short* x_bf   = (unsigned short*)alloc((size_t)Bb*Tseq*DM*2);
  unsigned short* qw_bf  = (unsigned short*)alloc((size_t)3*DM*DM*2);
  unsigned short* ow_bf  = (unsigned short*)alloc((size_t)DM*DM*2);
  unsigned short* qr     = (unsigned short*)alloc((size_t)Bb*NH*Tseq*64*2);
  unsigned short* kr     = (unsigned short*)alloc((size_t)Bb*NH*Tseq*64*2);
  unsigned short* vt     = (unsigned short*)alloc((size_t)Bb*NH*Tseq*64*2);
  unsigned short* ao     = (unsigned short*)alloc((size_t)Bb*Tseq*DM*2);
  (void)ws_size; (void)in_sizes; (void)n_in; (void)out_size;

  const int nx  = Bb*Tseq*DM;
  const int nqw = 3*DM*DM;
  const int now = DM*DM;
  k_convert3<<<2048, 256, 0, stream>>>(x, x_bf, nx, qkvw, qw_bf, nqw, outw, ow_bf, now);
  // qkv GEMM with fused RoPE epilogue (q->qr, k->kr) and fused V transpose (v->vt)
  k_gemm_bt<2><<<768, 256, 0, stream>>>(x_bf, qw_bf, nullptr, Bb*Tseq, 3*DM, DM, 3, qr, kr, vt);
  k_attn<<<dim3(Bb*NH*32), 256, 0, stream>>>(qr, kr, vt, ao);
  k_gemm_bt<0><<<256, 256, 0, stream>>>(ao, ow_bf, out, Bb*Tseq, DM, DM, 1, qr, kr, vt);
}

// Round 17
// 107.335 us; speedup vs baseline: 1.1528x; 1.1528x over previous
//
#include <hip/hip_runtime.h>
#include <hip/hip_bf16.h>
#include <cmath>

#define Bb   2
#define Tseq 2048
#define NH   16
#define DM   1024

using f32x4 = __attribute__((ext_vector_type(4))) float;
using s16x8 = __attribute__((ext_vector_type(8))) short;
using s16x4 = __attribute__((ext_vector_type(4))) short;

typedef const __attribute__((address_space(1))) unsigned char* as1p;
typedef __attribute__((address_space(3))) unsigned char* as3p;

static __device__ __forceinline__ void gload_lds16(const void* g, void* l){
  __builtin_amdgcn_global_load_lds((as1p)g, (as3p)l, 16, 0, 0);
}

// PV MFMA: 16x16x16 bf16 (K=16). B-frag needs P[k=g*4+j][q=ln] == QK^T output s[nt][r].
#if defined(__has_builtin)
#if __has_builtin(__builtin_amdgcn_mfma_f32_16x16x16bf16_1k)
#define MFMA16(acc, va, pb) (acc) = __builtin_amdgcn_mfma_f32_16x16x16bf16_1k((va), (pb), (acc), 0, 0, 0)
#endif
#endif
#ifndef MFMA16
#define MFMA16(acc, va, pb) asm volatile("s_nop 1\n\tv_mfma_f32_16x16x16_bf16 %0, %1, %2, %0" : "+v"(acc) : "v"(va), "v"(pb))
#endif

static __device__ __forceinline__ float b2f(unsigned short u){
  union { unsigned int u; float f; } v; v.u = ((unsigned int)u) << 16; return v.f;
}
static __device__ __forceinline__ unsigned short f2b(float f){
  union { float f; unsigned int u; } v; v.f = f;
  unsigned int u = v.u;
  return (unsigned short)((u + 0x7fffu + ((u >> 16) & 1u)) >> 16);
}

// ---------------- fp32 -> bf16 convert, all three tensors in one launch ----------------
__global__ void k_convert3(const float* __restrict__ a, unsigned short* __restrict__ ab, int na,
                           const float* __restrict__ b, unsigned short* __restrict__ bb, int nb,
                           const float* __restrict__ c, unsigned short* __restrict__ cb, int nc){
  const int q0 = na >> 2, q1 = nb >> 2, q2 = nc >> 2;
  const int tot = q0 + q1 + q2;
  const int stride = gridDim.x * blockDim.x;
  for (int i = blockIdx.x * blockDim.x + threadIdx.x; i < tot; i += stride) {
    const float* src; unsigned short* dst; int j = i;
    if (j < q0) { src = a; dst = ab; }
    else { j -= q0; if (j < q1) { src = b; dst = bb; } else { j -= q1; src = c; dst = cb; } }
    float4 v = reinterpret_cast<const float4*>(src)[j];
    ushort4 o; o.x = f2b(v.x); o.y = f2b(v.y); o.z = f2b(v.z); o.w = f2b(v.w);
    reinterpret_cast<ushort4*>(dst)[j] = o;
  }
}

// ---------------- GEMM  C[m,n] = sum_k A[m,k] * W[n,k] ----------------
// BK=64, gload_lds w16 with pre-swizzled SOURCE (linear dest + inverse-swz src
// + swz read; 0 bank conflicts verified r11). XCD-chunked 1D grid.
// MODE 0: fp32 C out. MODE 2: qkv fused epilogue -- q/k get in-register RoPE
// (on-the-fly __sincosf, q pre-scaled by 0.125*log2e); v tiles are transposed
// in the (dead) As/Bs LDS and written straight to vt[b,h,d,t] (vtrans fused).
template<int MODE>
__global__ __launch_bounds__(256) void k_gemm_bt(const unsigned short* __restrict__ A,
                                                 const unsigned short* __restrict__ W,
                                                 void* __restrict__ Cout,
                                                 int M, int N, int K, int NYL,
                                                 unsigned short* __restrict__ qr,
                                                 unsigned short* __restrict__ kr,
                                                 unsigned short* __restrict__ vt){
  __shared__ unsigned short As[128*64];
  __shared__ unsigned short Bs[128*64];
  const int i = (int)blockIdx.x;
  const int xcd = i & 7, rr = i >> 3;
  const int bx = rr / NYL, by = xcd * NYL + (rr % NYL);
  const int bm = bx * 128, bn = by * 128;
  const int tid = threadIdx.x;
  const int lane = tid & 63, w = tid >> 6;
  const int wr = w >> 1, wc = w & 1;            // wave -> 64x64 quadrant
  const int g = lane >> 4, ln = lane & 15;
  f32x4 acc[4][4] = {};
  char* asb = (char*)As + w * 4096;
  char* bsb = (char*)Bs + w * 4096;
  const int lrow8 = lane >> 3;                   // 0..7: row within 8-row gload group
  const int kcolb = ((lane & 7) ^ lrow8) * 16;   // byte col in 128B row window, pre-swz
  const size_t aro = (size_t)(bm + w * 32 + lrow8) * K;
  const size_t bro = (size_t)(bn + w * 32 + lrow8) * K;
  const int xr = (ln & 7) << 4;                  // read-side XOR (row&7 == ln&7)
  for (int k0 = 0; k0 < K; k0 += 64) {
    #pragma unroll
    for (int q4 = 0; q4 < 4; ++q4) {
      gload_lds16((const char*)(A + aro + (size_t)(q4 * 8) * K + k0) + kcolb, asb + q4 * 1024);
      gload_lds16((const char*)(W + bro + (size_t)(q4 * 8) * K + k0) + kcolb, bsb + q4 * 1024);
    }
    __syncthreads();
    #pragma unroll
    for (int kk = 0; kk < 2; ++kk) {
      s16x8 af[4], bfr[4];
      const int ro = (kk * 64 + g * 16) ^ xr;
      #pragma unroll
      for (int mt = 0; mt < 4; ++mt)
        af[mt] = *reinterpret_cast<const s16x8*>((char*)As + (wr*64 + mt*16 + ln) * 128 + ro);
      #pragma unroll
      for (int nt = 0; nt < 4; ++nt)
        bfr[nt] = *reinterpret_cast<const s16x8*>((char*)Bs + (wc*64 + nt*16 + ln) * 128 + ro);
      #pragma unroll
      for (int mt = 0; mt < 4; ++mt)
        #pragma unroll
        for (int nt = 0; nt < 4; ++nt)
          acc[mt][nt] = __builtin_amdgcn_mfma_f32_16x16x32_bf16(af[mt], bfr[nt], acc[mt][nt], 0, 0, 0);
    }
    __syncthreads();
  }
  // ---------------- epilogue ----------------
  if (MODE == 0) {
    #pragma unroll
    for (int mt = 0; mt < 4; ++mt)
      #pragma unroll
      for (int nt = 0; nt < 4; ++nt)
        #pragma unroll
        for (int r = 0; r < 4; ++r) {
          int row = bm + wr*64 + mt*16 + g*4 + r;     // D: row = (lane>>4)*4 + reg
          int col = bn + wc*64 + nt*16 + ln;          // D: col = lane&15
          reinterpret_cast<float*>(Cout)[(size_t)row * N + col] = acc[mt][nt][r];
        }
  } else {
    const int region = bn >> 10;                      // 0=q, 1=k, 2=v
    if (region == 2) {
      // V transpose in dead As/Bs LDS: [dcol 0..127][t 0..127] bf16 with XOR swizzle.
      unsigned short* tb = wc ? Bs : As;              // 64 rows x 256B each
      #pragma unroll
      for (int nt = 0; nt < 4; ++nt) {
        const int lrow = nt * 16 + ln;
        char* rowp = (char*)tb + lrow * 256;
        const int sx = (lrow & 15) << 3;
        #pragma unroll
        for (int mt = 0; mt < 4; ++mt) {
          const int t2 = (wr*64 + mt*16 + g*4) * 2;   // byte offset, 8B-aligned
          unsigned int lo = (unsigned int)f2b(acc[mt][nt][0]) | ((unsigned int)f2b(acc[mt][nt][1]) << 16);
          unsigned int hi = (unsigned int)f2b(acc[mt][nt][2]) | ((unsigned int)f2b(acc[mt][nt][3]) << 16);
          *reinterpret_cast<uint2*>(rowp + (t2 ^ sx)) = make_uint2(lo, hi);
        }
      }
      __syncthreads();
      {
        const int dcol = tid >> 1, half = tid & 1;    // 64 t's (=128B) per thread
        unsigned short* tb2 = (dcol < 64) ? As : Bs;
        char* rowp = (char*)tb2 + (dcol & 63) * 256;
        const int sx = (dcol & 15) << 3;
        unsigned int buf[32];
        #pragma unroll
        for (int k = 0; k < 16; ++k) {
          uint2 v = *reinterpret_cast<uint2*>(rowp + ((((half * 64 + k * 4) * 2) ^ sx)));
          buf[k*2] = v.x; buf[k*2+1] = v.y;
        }
        const int h0 = (bn - 2048) >> 6;
        const int hq = h0 + (dcol >> 6);
        const int dd = dcol & 63;
        const int row0 = bm + half * 64;
        const int b = row0 >> 11, t0 = row0 & (Tseq - 1);
        unsigned short* dst = vt + ((size_t)((b * NH + hq) * 64 + dd)) * Tseq + t0;
        #pragma unroll
        for (int k = 0; k < 8; ++k)
          reinterpret_cast<uint4*>(dst)[k] = make_uint4(buf[k*4], buf[k*4+1], buf[k*4+2], buf[k*4+3]);
      }
    } else {
      // RoPE in-register: dd = nt*16+ln (wc-independent); pairs (nt, nt^2) same lane.
      const float if0 = exp2f(-(float)ln        * 0.4152410118074f);
      const float if1 = exp2f(-(float)(16 + ln) * 0.4152410118074f);
      const int h = ((bn + wc * 64) >> 6) & 15;
      unsigned short* dst = (region == 0) ? qr : kr;
      // q: fold 1/sqrt(dh) AND log2(e) so attention uses native exp2
      const float qs = (region == 0) ? 0.18033688011112042f : 1.0f;
      #pragma unroll
      for (int mt = 0; mt < 4; ++mt)
        #pragma unroll
        for (int r = 0; r < 4; ++r) {
          int row = bm + wr*64 + mt*16 + g*4 + r;
          int t = row & (Tseq - 1), b = row >> 11;
          float c0, s0, c1, s1;
          __sincosf((float)t * if0, &s0, &c0);
          __sincosf((float)t * if1, &s1, &c1);
          float v0 = (acc[mt][0][r] * c0 - acc[mt][2][r] * s0) * qs;  // dd=ln
          float v1 = (acc[mt][1][r] * c1 - acc[mt][3][r] * s1) * qs;  // dd=16+ln
          float v2 = (acc[mt][2][r] * c0 + acc[mt][0][r] * s0) * qs;  // dd=32+ln
          float v3 = (acc[mt][3][r] * c1 + acc[mt][1][r] * s1) * qs;  // dd=48+ln
          size_t base = ((size_t)(b * NH + h) * Tseq + t) * 64 + ln;
          dst[base]      = f2b(v0);
          dst[base + 16] = f2b(v1);
          dst[base + 32] = f2b(v2);
          dst[base + 48] = f2b(v3);
        }
    }
  }
}

// ---------------- causal flash attention, fully-swapped, dbuf + reg-P (r15-exact) ----------------
// 256-thr blocks (4 waves x 16 q), paired q-tiles (j, 31-j): 33 visits, 512 blocks
// = 2/CU, XCD-chunked (4 heads/XCD L2-resident). K/V reg-staged, 16B-granular swizzle.
// launch_bounds(256,2): VGPR 68 needed for hoisted K/V prefetch (r16: forcing 5 blk/CU
// cut VGPR to 48, serialized the prefetch, -35% perf). exp2-domain softmax + trunc-pack.
__global__ __launch_bounds__(256, 2) void k_attn(const unsigned short* __restrict__ Qr,
                                                 const unsigned short* __restrict__ Kr,
                                                 const unsigned short* __restrict__ Vt,
                                                 unsigned short* __restrict__ Ao){
  __shared__ unsigned short Ks[2][64*64];
  __shared__ unsigned short Vs[2][64*64];
  __shared__ unsigned short Ps[4][16*72];
  // XCD-chunked bijective remap: 512 = 8 xcds x (4 heads x 16 pj)
  const int i = (int)blockIdx.x;
  const int xcd = i & 7, r = i >> 3;
  const int bh = xcd * 4 + (r >> 4);
  const int pj = r & 15;
  const unsigned short* Q  = Qr + (size_t)bh * Tseq * 64;
  const unsigned short* Kp = Kr + (size_t)bh * Tseq * 64;
  const unsigned short* Vp = Vt + (size_t)bh * 64 * Tseq;
  const int tid = threadIdx.x;
  const int w = tid >> 6, lane = tid & 63;
  const int g = lane >> 4, ln = lane & 15;
  // staging: 256 thr x 32B of each 8KB tile. row = tid>>2, chunk pair = (tid&3)*2
  const int srow = tid >> 2;
  const int c2 = (tid & 3) * 2;
  const int scol = c2 * 8;                          // shorts
  const int swz = (srow & 7) << 4;
  const int wb0 = srow * 128 + ((c2 * 16)      ^ swz);
  const int wb1 = srow * 128 + ((c2 * 16 + 16) ^ swz);
  // QK frag read offsets (b128)
  const int x0 = (g * 16)      ^ ((ln & 7) << 4);
  const int x1 = (64 + g * 16) ^ ((ln & 7) << 4);
  unsigned short* Pw = Ps[w];
  const int b = bh / NH, h = bh % NH;

  #pragma unroll
  for (int pass = 0; pass < 2; ++pass) {
    const int j = pass ? (31 - pj) : pj;            // paired q-tiles: 33 visits total
    const int q0 = j * 64;
    const int ntiles = j + 1;
    const int q0w = q0 + w * 16;

    s16x8 qf0 = *reinterpret_cast<const s16x8*>(&Q[(size_t)(q0w + ln) * 64 + g * 8]);
    s16x8 qf1 = *reinterpret_cast<const s16x8*>(&Q[(size_t)(q0w + ln) * 64 + 32 + g * 8]);

    f32x4 oacc[4] = {};
    float lsum = 0.f;

    // prologue: stage tile 0 into buf 0
    {
      const unsigned short* gk = Kp + (size_t)srow * 64 + scol;
      const unsigned short* gv = Vp + (size_t)srow * Tseq + scol;
      uint4 k0 = *reinterpret_cast<const uint4*>(gk);
      uint4 k1 = *reinterpret_cast<const uint4*>(gk + 8);
      uint4 v0 = *reinterpret_cast<const uint4*>(gv);
      uint4 v1 = *reinterpret_cast<const uint4*>(gv + 8);
      *reinterpret_cast<uint4*>((char*)Ks[0] + wb0) = k0;
      *reinterpret_cast<uint4*>((char*)Ks[0] + wb1) = k1;
      *reinterpret_cast<uint4*>((char*)Vs[0] + wb0) = v0;
      *reinterpret_cast<uint4*>((char*)Vs[0] + wb1) = v1;
    }
    __syncthreads();
    int cur = 0;

    for (int kt = 0; kt < ntiles; ++kt) {
      const bool pre = (kt + 1 < ntiles);
      const int nxt = cur ^ 1;
      uint4 nk0, nk1, nv0, nv1;
      if (pre) {  // issue next-tile loads early; L2-hit latency hides under compute
        const unsigned short* gk = Kp + (size_t)((kt + 1) * 64 + srow) * 64 + scol;
        const unsigned short* gv = Vp + (size_t)srow * Tseq + (kt + 1) * 64 + scol;
        nk0 = *reinterpret_cast<const uint4*>(gk);
        nk1 = *reinterpret_cast<const uint4*>(gk + 8);
        nv0 = *reinterpret_cast<const uint4*>(gv);
        nv1 = *reinterpret_cast<const uint4*>(gv + 8);
      }
      // ---- QK^T swapped: s[nt] = S^T[k = kt*64+nt*16+g*4+r][q = q0w+ln] ----
      f32x4 s[4] = {};
      const char* kb = (const char*)Ks[cur];
      __builtin_amdgcn_s_setprio(1);
      #pragma unroll
      for (int nt = 0; nt < 4; ++nt) {
        s16x8 kfa = *reinterpret_cast<const s16x8*>(kb + nt * 2048 + ln * 128 + x0);
        s16x8 kfb = *reinterpret_cast<const s16x8*>(kb + nt * 2048 + ln * 128 + x1);
        s[nt] = __builtin_amdgcn_mfma_f32_16x16x32_bf16(kfa, qf0, s[nt], 0, 0, 0);
        s[nt] = __builtin_amdgcn_mfma_f32_16x16x32_bf16(kfb, qf1, s[nt], 0, 0, 0);
      }
      __builtin_amdgcn_s_setprio(0);
      // ---- causal mask (last tile only; k_rel = nt*16+g*4+r, q_rel = w*16+ln) ----
      if (kt == ntiles - 1) {
        #pragma unroll
        for (int nt = 0; nt < 4; ++nt)
          #pragma unroll
          for (int r2 = 0; r2 < 4; ++r2)
            if (nt * 16 + g * 4 + r2 > w * 16 + ln) s[nt][r2] = -1e30f;
      }
      // ---- fixed-base softmax, exp2 domain (q pre-scaled by log2e/8);
      //      raw v_exp_f32 via builtin; P packed to bf16 by truncation ----
      s16x4 pb[4];
      #pragma unroll
      for (int nt = 0; nt < 4; ++nt)
        #pragma unroll
        for (int r2 = 0; r2 < 4; ++r2) {
          float p = __builtin_amdgcn_exp2f(s[nt][r2]);
          lsum += p;
          pb[nt][r2] = (short)(__float_as_uint(p) >> 16);
        }
      // ---- PV via 16x16x16: oacc[dt] = O^T[d = dt*16+g*4+r][q = ln] ----
      const char* vb = (const char*)Vs[cur];
      __builtin_amdgcn_s_setprio(1);
      #pragma unroll
      for (int dt = 0; dt < 4; ++dt) {
        #pragma unroll
        for (int nt = 0; nt < 4; ++nt) {
          s16x4 va = *reinterpret_cast<const s16x4*>(vb + (dt * 16 + ln) * 128 + ((nt * 32 + g * 8) ^ ((ln & 7) << 4)));
          MFMA16(oacc[dt], va, pb[nt]);
        }
      }
      __builtin_amdgcn_s_setprio(0);
      // ---- write prefetched tile into other buffer; single barrier ----
      if (pre) {
        *reinterpret_cast<uint4*>((char*)Ks[nxt] + wb0) = nk0;
        *reinterpret_cast<uint4*>((char*)Ks[nxt] + wb1) = nk1;
        *reinterpret_cast<uint4*>((char*)Vs[nxt] + wb0) = nv0;
        *reinterpret_cast<uint4*>((char*)Vs[nxt] + wb1) = nv1;
      }
      __syncthreads();
      cur ^= 1;
    }

    // ---- epilogue: l-reduce, O^T -> row-major via LDS bounce, coalesced stores ----
    float l = lsum;
    l += __shfl_xor(l, 16);
    l += __shfl_xor(l, 32);
    float inv = 1.f / l;
    #pragma unroll
    for (int nt = 0; nt < 4; ++nt) {
      unsigned int lo = (unsigned int)f2b(oacc[nt][0] * inv) | ((unsigned int)f2b(oacc[nt][1] * inv) << 16);
      unsigned int hi = (unsigned int)f2b(oacc[nt][2] * inv) | ((unsigned int)f2b(oacc[nt][3] * inv) << 16);
      *reinterpret_cast<uint2*>(&Pw[ln * 72 + nt * 16 + g * 4]) = make_uint2(lo, hi);
    }
    asm volatile("s_waitcnt lgkmcnt(0)" ::: "memory");
    __builtin_amdgcn_sched_barrier(0);
    const int rr2 = lane >> 2;                // 0..15: q-row within wave tile
    const int cc = (lane & 3) * 8;            // short offset
    uint4 ov0 = *reinterpret_cast<const uint4*>(&Pw[rr2 * 72 + cc]);
    uint4 ov1 = *reinterpret_cast<const uint4*>(&Pw[rr2 * 72 + cc + 32]);
    int t = q0w + rr2;
    unsigned short* orow = &Ao[((size_t)(b * Tseq + t) * DM) + h * 64];
    *reinterpret_cast<uint4*>(orow + cc)      = ov0;
    *reinterpret_cast<uint4*>(orow + cc + 32) = ov1;
  }
}

extern "C" void kernel_launch(void* const* d_in, const int* in_sizes, int n_in,
                              void* d_out, int out_size, void* d_ws, size_t ws_size,
                              hipStream_t stream) {
  const float* x    = (const float*)d_in[0];
  const float* qkvw = (const float*)d_in[1];
  const float* outw = (const float*)d_in[2];
  float* out = (float*)d_out;
  char* ws = (char*)d_ws;
  size_t off = 0;
  auto alloc = [&](size_t bytes)->void*{ void* p = ws + off; off += (bytes + 255) & ~(size_t)255; return p; };
  unsigned short* x_bf   = (unsigned short*)alloc((size_t)Bb*Tseq*DM*2);
  unsigned short* qw_bf  = (unsigned short*)alloc((size_t)3*DM*DM*2);
  unsigned short* ow_bf  = (unsigned short*)alloc((size_t)DM*DM*2);
  unsigned short* qr     = (unsigned short*)alloc((size_t)Bb*NH*Tseq*64*2);
  unsigned short* kr     = (unsigned short*)alloc((size_t)Bb*NH*Tseq*64*2);
  unsigned short* vt     = (unsigned short*)alloc((size_t)Bb*NH*Tseq*64*2);
  unsigned short* ao     = (unsigned short*)alloc((size_t)Bb*Tseq*DM*2);
  (void)ws_size; (void)in_sizes; (void)n_in; (void)out_size;

  const int nx  = Bb*Tseq*DM;
  const int nqw = 3*DM*DM;
  const int now = DM*DM;
  k_convert3<<<2048, 256, 0, stream>>>(x, x_bf, nx, qkvw, qw_bf, nqw, outw, ow_bf, now);
  // qkv GEMM with fused RoPE epilogue (q->qr, k->kr) and fused V transpose (v->vt)
  k_gemm_bt<2><<<768, 256, 0, stream>>>(x_bf, qw_bf, nullptr, Bb*Tseq, 3*DM, DM, 3, qr, kr, vt);
  k_attn<<<dim3(Bb*NH*16), 256, 0, stream>>>(qr, kr, vt, ao);
  k_gemm_bt<0><<<256, 256, 0, stream>>>(ao, ow_bf, out, Bb*Tseq, DM, DM, 1, qr, kr, vt);
}